// Round 10
// baseline (175.265 us; speedup 1.0000x reference)
//
#include <hip/hip_runtime.h>
#include <hip/hip_bf16.h>
#include <math.h>

#define B_   2
#define L_   1024
#define DM   1024
#define DI   2048
#define NS   16
#define NPJ  33
#define XPW_STRIDE 64   // padded x_proj rows / xp row stride
#define NCH  64     // chunks
#define CHL  16     // chunk length

typedef __bf16 bf16x8 __attribute__((ext_vector_type(8)));
typedef float  f32x4  __attribute__((ext_vector_type(4)));

__device__ __forceinline__ unsigned short f2bf_rn(float x) {
    union { float f; unsigned u; } a; a.f = x;
    unsigned r = a.u + 0x7fffu + ((a.u >> 16) & 1u);
    return (unsigned short)(r >> 16);
}
__device__ __forceinline__ float bf2f(unsigned short h) {
    union { unsigned u; float f; } a; a.u = ((unsigned)h) << 16;
    return a.f;
}
__device__ __forceinline__ float sigmoidf_(float x) { return 1.f / (1.f + __expf(-x)); }
__device__ __forceinline__ float softplusf_(float x) {
    return x > 20.f ? x : log1pf(__expf(x));
}

#define GLDS(g, l) __builtin_amdgcn_global_load_lds( \
    (__attribute__((address_space(1))) void*)(g),    \
    (__attribute__((address_space(3))) void*)(l), 16, 0, 0)

// ---------------- fused cast ----------------
// x -> hi only; w1 -> hi/lo pair (folded GEMM1 reads both); w2 -> hi only;
// x_proj_w -> padded hi/lo pair.
#define XN4   524288          // 2048*1024/4
#define W1N4  1048576         // 4096*1024/4
#define W2N4  524288          // 1024*2048/4
#define WPN4  32768           // 64*2048/4
__global__ __launch_bounds__(256) void cast_all_kernel(
    const float* __restrict__ x, const float* __restrict__ w1,
    const float* __restrict__ w2, const float* __restrict__ xpw,
    unsigned short* __restrict__ xh,
    unsigned short* __restrict__ w1h, unsigned short* __restrict__ w1l,
    unsigned short* __restrict__ w2h,
    unsigned short* __restrict__ wph, unsigned short* __restrict__ wpl)
{
    int i = blockIdx.x * 256 + threadIdx.x;
    if (i < XN4) {
        float4 v = ((const float4*)x)[i];
        ushort4 H;
        H.x = f2bf_rn(v.x); H.y = f2bf_rn(v.y); H.z = f2bf_rn(v.z); H.w = f2bf_rn(v.w);
        ((ushort4*)xh)[i] = H;
    } else if (i < XN4 + W1N4) {
        int li = i - XN4;
        float4 v = ((const float4*)w1)[li];
        ushort4 H, L;
        H.x = f2bf_rn(v.x); L.x = f2bf_rn(v.x - bf2f(H.x));
        H.y = f2bf_rn(v.y); L.y = f2bf_rn(v.y - bf2f(H.y));
        H.z = f2bf_rn(v.z); L.z = f2bf_rn(v.z - bf2f(H.z));
        H.w = f2bf_rn(v.w); L.w = f2bf_rn(v.w - bf2f(H.w));
        ((ushort4*)w1h)[li] = H; ((ushort4*)w1l)[li] = L;
    } else if (i < XN4 + W1N4 + W2N4) {
        int li = i - (XN4 + W1N4);
        float4 v = ((const float4*)w2)[li];
        ushort4 H;
        H.x = f2bf_rn(v.x); H.y = f2bf_rn(v.y); H.z = f2bf_rn(v.z); H.w = f2bf_rn(v.w);
        ((ushort4*)w2h)[li] = H;
    } else if (i < XN4 + W1N4 + W2N4 + WPN4) {
        int li = i - (XN4 + W1N4 + W2N4);
        int j = li >> 9;
        float4 v = (j < NPJ) ? ((const float4*)xpw)[li] : make_float4(0.f, 0.f, 0.f, 0.f);
        ushort4 H, L;
        H.x = f2bf_rn(v.x); L.x = f2bf_rn(v.x - bf2f(H.x));
        H.y = f2bf_rn(v.y); L.y = f2bf_rn(v.y - bf2f(H.y));
        H.z = f2bf_rn(v.z); L.z = f2bf_rn(v.z - bf2f(H.z));
        H.w = f2bf_rn(v.w); L.w = f2bf_rn(v.w - bf2f(H.w));
        ((ushort4*)wph)[li] = H; ((ushort4*)wpl)[li] = L;
    }
}

// ---------------- folded GEMM1: C[m][n] = sum_k x[m][k]*(W1h[n][k] ++ W1l[n][k]) ----------------
// Logical K=2048 = two halves; B base switches at kt=1024, A column = kt & 1023.
// 1-term inner loop, LDS 32KB -> ~5 blocks/CU.
template<int BM, int BN>
__global__ __launch_bounds__(256) void gemm_fold(
    const unsigned short* __restrict__ Ah,
    const unsigned short* __restrict__ B0, const unsigned short* __restrict__ B1,
    float* __restrict__ C, int M, int N, int KH)   // KH = 1024 (half-K, also A/B row stride)
{
    constexpr int BK = 64;
    constexpr int FM = BM / 32;
    constexpr int FN = BN / 32;
    __shared__ alignas(16) char sAh[BM * BK * 2];
    __shared__ alignas(16) char sBh[BN * BK * 2];

    const int tid  = threadIdx.x;
    const int lane = tid & 63;
    const int wave = tid >> 6;
    const int wm = wave >> 1, wn = wave & 1;
    const int m0 = blockIdx.y * BM, n0 = blockIdx.x * BN;

    f32x4 acc[FM][FN];
#pragma unroll
    for (int i = 0; i < FM; ++i)
#pragma unroll
        for (int j = 0; j < FN; ++j)
            acc[i][j] = (f32x4){0.f, 0.f, 0.f, 0.f};

    for (int kt = 0; kt < 2 * 1024; kt += BK) {
        const unsigned short* Bb = (kt < 1024) ? B0 : B1;
        const int kc = kt & 1023;
#pragma unroll
        for (int iss = 0; iss < BM / 32; ++iss) {
            int o  = (iss * 256 + tid) * 16;
            int r  = o >> 7;
            int cb = (o & 127) ^ ((r & 7) << 4);
            size_t goff = (size_t)(m0 + r) * KH + kc + (cb >> 1);
            GLDS(Ah + goff, sAh + iss * 4096 + wave * 1024);
        }
#pragma unroll
        for (int iss = 0; iss < BN / 32; ++iss) {
            int o  = (iss * 256 + tid) * 16;
            int r  = o >> 7;
            int cb = (o & 127) ^ ((r & 7) << 4);
            size_t goff = (size_t)(n0 + r) * KH + kc + (cb >> 1);
            GLDS(Bb + goff, sBh + iss * 4096 + wave * 1024);
        }
        __syncthreads();

#pragma unroll
        for (int kk = 0; kk < 2; ++kk) {
            const int ke = kk * 32 + (lane >> 4) * 8;
            bf16x8 ah[FM], bh[FN];
#pragma unroll
            for (int i = 0; i < FM; ++i) {
                int r = wm * (BM / 2) + i * 16 + (lane & 15);
                int off = (r * 128 + ke * 2) ^ ((r & 7) << 4);
                ah[i] = *(const bf16x8*)(sAh + off);
            }
#pragma unroll
            for (int j = 0; j < FN; ++j) {
                int r = wn * (BN / 2) + j * 16 + (lane & 15);
                int off = (r * 128 + ke * 2) ^ ((r & 7) << 4);
                bh[j] = *(const bf16x8*)(sBh + off);
            }
#pragma unroll
            for (int i = 0; i < FM; ++i)
#pragma unroll
                for (int j = 0; j < FN; ++j)
                    acc[i][j] = __builtin_amdgcn_mfma_f32_16x16x32_bf16(ah[i], bh[j], acc[i][j], 0, 0, 0);
        }
        __syncthreads();
    }

#pragma unroll
    for (int i = 0; i < FM; ++i)
#pragma unroll
        for (int j = 0; j < FN; ++j) {
            int row = m0 + wm * (BM / 2) + i * 16 + (lane >> 4) * 4;
            int col = n0 + wn * (BN / 2) + j * 16 + (lane & 15);
            float* p = C + (size_t)row * N + col;
#pragma unroll
            for (int q = 0; q < 4; ++q) p[(size_t)q * N] = acc[i][j][q];
        }
}

// ---------------- 1-term GEMM (GEMM2): C[m][n] = sum_k A[m][k]*B[n][k], split-K ----------------
template<int BM, int BN>
__global__ __launch_bounds__(256) void gemm_bt1(
    const unsigned short* __restrict__ Ah, const unsigned short* __restrict__ Bh,
    float* __restrict__ C, int M, int N, int K, int KC)
{
    constexpr int BK = 64;
    constexpr int FM = BM / 32;
    constexpr int FN = BN / 32;
    __shared__ alignas(16) char sAh[BM * BK * 2];
    __shared__ alignas(16) char sBh[BN * BK * 2];

    const int tid  = threadIdx.x;
    const int lane = tid & 63;
    const int wave = tid >> 6;
    const int wm = wave >> 1, wn = wave & 1;
    const int m0 = blockIdx.y * BM, n0 = blockIdx.x * BN;
    const int k0 = blockIdx.z * KC;

    f32x4 acc[FM][FN];
#pragma unroll
    for (int i = 0; i < FM; ++i)
#pragma unroll
        for (int j = 0; j < FN; ++j)
            acc[i][j] = (f32x4){0.f, 0.f, 0.f, 0.f};

    for (int kt = k0; kt < k0 + KC; kt += BK) {
#pragma unroll
        for (int iss = 0; iss < BM / 32; ++iss) {
            int o  = (iss * 256 + tid) * 16;
            int r  = o >> 7;
            int cb = (o & 127) ^ ((r & 7) << 4);
            size_t goff = (size_t)(m0 + r) * K + kt + (cb >> 1);
            GLDS(Ah + goff, sAh + iss * 4096 + wave * 1024);
        }
#pragma unroll
        for (int iss = 0; iss < BN / 32; ++iss) {
            int o  = (iss * 256 + tid) * 16;
            int r  = o >> 7;
            int cb = (o & 127) ^ ((r & 7) << 4);
            size_t goff = (size_t)(n0 + r) * K + kt + (cb >> 1);
            GLDS(Bh + goff, sBh + iss * 4096 + wave * 1024);
        }
        __syncthreads();

#pragma unroll
        for (int kk = 0; kk < 2; ++kk) {
            const int ke = kk * 32 + (lane >> 4) * 8;
            bf16x8 ah[FM], bh[FN];
#pragma unroll
            for (int i = 0; i < FM; ++i) {
                int r = wm * (BM / 2) + i * 16 + (lane & 15);
                int off = (r * 128 + ke * 2) ^ ((r & 7) << 4);
                ah[i] = *(const bf16x8*)(sAh + off);
            }
#pragma unroll
            for (int j = 0; j < FN; ++j) {
                int r = wn * (BN / 2) + j * 16 + (lane & 15);
                int off = (r * 128 + ke * 2) ^ ((r & 7) << 4);
                bh[j] = *(const bf16x8*)(sBh + off);
            }
#pragma unroll
            for (int i = 0; i < FM; ++i)
#pragma unroll
                for (int j = 0; j < FN; ++j)
                    acc[i][j] = __builtin_amdgcn_mfma_f32_16x16x32_bf16(ah[i], bh[j], acc[i][j], 0, 0, 0);
        }
        __syncthreads();
    }

    float* Cz = C + (size_t)blockIdx.z * M * N;
#pragma unroll
    for (int i = 0; i < FM; ++i)
#pragma unroll
        for (int j = 0; j < FN; ++j) {
            int row = m0 + wm * (BM / 2) + i * 16 + (lane >> 4) * 4;
            int col = n0 + wn * (BN / 2) + j * 16 + (lane & 15);
            float* p = Cz + (size_t)row * N + col;
#pragma unroll
            for (int q = 0; q < 4; ++q) p[(size_t)q * N] = acc[i][j][q];
        }
}

// ---------------- reduce 4 split-K partials ----------------
__global__ __launch_bounds__(256) void reduce4_kernel(
    const float* __restrict__ part, float* __restrict__ out, int n4, int stride4)
{
    int i = blockIdx.x * 256 + threadIdx.x;
    if (i >= n4) return;
    const float4* p = (const float4*)part;
    float4 s = p[i];
#pragma unroll
    for (int z = 1; z < 4; ++z) {
        float4 v = p[(size_t)z * stride4 + i];
        s.x += v.x; s.y += v.y; s.z += v.z; s.w += v.w;
    }
    ((float4*)out)[i] = s;
}

// ---------------- x_proj split-K GEMM (2-term: xch x (Wph,Wpl)) ----------------
__global__ __launch_bounds__(256) void gemm2_xproj(
    const unsigned short* __restrict__ Ah,
    const unsigned short* __restrict__ Bh, const unsigned short* __restrict__ Bl,
    float* __restrict__ part)
{
    constexpr int BM = 64, BN = 64, BK = 64, KTOT = 2048, KC = 256;
    __shared__ alignas(16) char sAh[BM * 128];
    __shared__ alignas(16) char sBh[BN * 128];
    __shared__ alignas(16) char sBl[BN * 128];

    const int tid  = threadIdx.x;
    const int lane = tid & 63;
    const int wave = tid >> 6;
    const int wm = wave >> 1, wn = wave & 1;
    const int m0 = blockIdx.y * BM;
    const int kt0 = blockIdx.z * KC;

    f32x4 acc[2][2];
#pragma unroll
    for (int i = 0; i < 2; ++i)
#pragma unroll
        for (int j = 0; j < 2; ++j) acc[i][j] = (f32x4){0.f, 0.f, 0.f, 0.f};

    for (int kt = 0; kt < KC; kt += BK) {
#pragma unroll
        for (int iss = 0; iss < 2; ++iss) {
            int o  = (iss * 256 + tid) * 16;
            int r  = o >> 7;
            int cb = (o & 127) ^ ((r & 7) << 4);
            size_t ga = (size_t)(m0 + r) * KTOT + kt0 + kt + (cb >> 1);
            GLDS(Ah + ga, sAh + iss * 4096 + wave * 1024);
            size_t gb = (size_t)r * KTOT + kt0 + kt + (cb >> 1);
            GLDS(Bh + gb, sBh + iss * 4096 + wave * 1024);
            GLDS(Bl + gb, sBl + iss * 4096 + wave * 1024);
        }
        __syncthreads();

#pragma unroll
        for (int kk = 0; kk < 2; ++kk) {
            const int ke = kk * 32 + (lane >> 4) * 8;
            bf16x8 ah[2], bh[2], bl[2];
#pragma unroll
            for (int i = 0; i < 2; ++i) {
                int r = wm * 32 + i * 16 + (lane & 15);
                int off = (r * 128 + ke * 2) ^ ((r & 7) << 4);
                ah[i] = *(const bf16x8*)(sAh + off);
            }
#pragma unroll
            for (int j = 0; j < 2; ++j) {
                int r = wn * 32 + j * 16 + (lane & 15);
                int off = (r * 128 + ke * 2) ^ ((r & 7) << 4);
                bh[j] = *(const bf16x8*)(sBh + off);
                bl[j] = *(const bf16x8*)(sBl + off);
            }
#pragma unroll
            for (int i = 0; i < 2; ++i)
#pragma unroll
                for (int j = 0; j < 2; ++j) {
                    acc[i][j] = __builtin_amdgcn_mfma_f32_16x16x32_bf16(ah[i], bh[j], acc[i][j], 0, 0, 0);
                    acc[i][j] = __builtin_amdgcn_mfma_f32_16x16x32_bf16(ah[i], bl[j], acc[i][j], 0, 0, 0);
                }
        }
        __syncthreads();
    }

    float* Cp = part + (size_t)blockIdx.z * 2048 * XPW_STRIDE;
#pragma unroll
    for (int i = 0; i < 2; ++i)
#pragma unroll
        for (int j = 0; j < 2; ++j) {
            int row = m0 + wm * 32 + i * 16 + (lane >> 4) * 4;
            int col = wn * 32 + j * 16 + (lane & 15);
            float* p = Cp + (size_t)row * XPW_STRIDE + col;
#pragma unroll
            for (int q = 0; q < 4; ++q) p[(size_t)q * XPW_STRIDE] = acc[i][j][q];
        }
}

// ---------------- reduce split-K partials: xp = sum_z part[z] ----------------
__global__ __launch_bounds__(256) void xproj_reduce(
    const float* __restrict__ part, float* __restrict__ xp)
{
    int i = blockIdx.x * 256 + threadIdx.x;   // over 2048*64/4 = 32768 float4
    const float4* p = (const float4*)part;
    float4 s = p[i];
#pragma unroll
    for (int z = 1; z < 8; ++z) {
        float4 v = p[(size_t)z * 32768 + i];
        s.x += v.x; s.y += v.y; s.z += v.z; s.w += v.w;
    }
    ((float4*)xp)[i] = s;
}

// ---------------- causal conv(4) + silu -> bf16 ----------------
__global__ __launch_bounds__(256) void conv_silu_kernel(
    const float* __restrict__ xz, const float* __restrict__ cw,
    const float* __restrict__ cb, unsigned short* __restrict__ xch)
{
    int gid = blockIdx.x * 256 + threadIdx.x;   // 2048 rows * 512 vec4
    int m  = gid >> 9;
    int dv = (gid & 511) << 2;
    int t  = m & (L_ - 1);
    const float* base = xz + (size_t)m * (2 * DI) + dv;
    float4 s  = *(const float4*)(cb + dv);
    float4 w0 = *(const float4*)(cw + (dv + 0) * 4);
    float4 w1 = *(const float4*)(cw + (dv + 1) * 4);
    float4 w2 = *(const float4*)(cw + (dv + 2) * 4);
    float4 w3 = *(const float4*)(cw + (dv + 3) * 4);
    float4 z4 = make_float4(0.f, 0.f, 0.f, 0.f);
    float4 x3 = *(const float4*)(base);
    float4 x2 = (t >= 1) ? *(const float4*)(base - 1 * (2 * DI)) : z4;
    float4 x1 = (t >= 2) ? *(const float4*)(base - 2 * (2 * DI)) : z4;
    float4 x0 = (t >= 3) ? *(const float4*)(base - 3 * (2 * DI)) : z4;
    float r0 = s.x + w0.x * x0.x + w0.y * x1.x + w0.z * x2.x + w0.w * x3.x;
    float r1 = s.y + w1.x * x0.y + w1.y * x1.y + w1.z * x2.y + w1.w * x3.y;
    float r2 = s.z + w2.x * x0.z + w2.y * x1.z + w2.z * x2.z + w2.w * x3.z;
    float r3 = s.w + w3.x * x0.w + w3.y * x1.w + w3.z * x2.w + w3.w * x3.w;
    ushort4 H;
    float o0 = r0 * sigmoidf_(r0);
    float o1 = r1 * sigmoidf_(r1);
    float o2 = r2 * sigmoidf_(r2);
    float o3 = r3 * sigmoidf_(r3);
    H.x = f2bf_rn(o0); H.y = f2bf_rn(o1); H.z = f2bf_rn(o2); H.w = f2bf_rn(o3);
    *(ushort4*)(xch + (size_t)m * DI + dv) = H;
}

// ---------------- scan pass 1: per-chunk local scan (h_in = 0) + sum(dt) ----------------
__global__ __launch_bounds__(256) void scan_pass1(
    const unsigned short* __restrict__ xch,
    const float* __restrict__ xp,
    const float* __restrict__ dtw, const float* __restrict__ dtb,
    const float* __restrict__ A_log, float* __restrict__ h0, float* __restrict__ sumdt)
{
    const int b = blockIdx.z, c = blockIdx.y;
    const int tid = threadIdx.x;
    const int d = blockIdx.x * 256 + tid;
    __shared__ float sxp[CHL * XPW_STRIDE];
    const float* xpsrc = xp + (size_t)(b * L_ + c * CHL) * XPW_STRIDE;
    for (int i = tid; i < CHL * XPW_STRIDE / 4; i += 256)
        ((float4*)sxp)[i] = ((const float4*)xpsrc)[i];
    __syncthreads();

    float Av[NS];
#pragma unroll
    for (int n = 0; n < NS; ++n) Av[n] = -__expf(A_log[(size_t)d * NS + n]);
    const float w = dtw[d], bb = dtb[d];
    float h[NS];
#pragma unroll
    for (int n = 0; n < NS; ++n) h[n] = 0.f;
    float sd = 0.f;
    size_t off = (size_t)(b * L_ + c * CHL) * DI + d;

    unsigned short nh = xch[off];
    for (int t = 0; t < CHL; ++t) {
        unsigned short ch = nh;
        nh = xch[off + DI];    // prefetch t+1 (last iter overruns, value unused)
        off += DI;
        float xcv = bf2f(ch);
        float dt  = softplusf_(fmaf(sxp[t * XPW_STRIDE], w, bb));
        sd += dt;
        float u = dt * xcv;
#pragma unroll
        for (int n = 0; n < NS; ++n) {
            float a = __expf(dt * Av[n]);
            h[n] = fmaf(a, h[n], u * sxp[t * XPW_STRIDE + 1 + n]);
        }
    }
    float* hp = h0 + ((size_t)(b * NCH + c) * DI + d) * NS;
#pragma unroll
    for (int n = 0; n < NS; n += 4)
        *(float4*)(hp + n) = make_float4(h[n], h[n + 1], h[n + 2], h[n + 3]);
    sumdt[(size_t)(b * NCH + c) * DI + d] = sd;
}

// ---------------- scan pass 2: chunk-level prefix (in place: h0 becomes h_in) ----------------
__global__ __launch_bounds__(256) void scan_pass2(
    const float* __restrict__ A_log, const float* __restrict__ sumdt, float* __restrict__ h0)
{
    int gid = blockIdx.x * 256 + threadIdx.x;   // B_*DI*NS = 65536
    int b = gid >> 15;
    int r = gid & 32767;
    int d = r >> 4, n = r & 15;
    float An = -__expf(A_log[(size_t)d * NS + n]);
    float h = 0.f;
    for (int cb = 0; cb < NCH; cb += 16) {
        float hl[16], e[16];
#pragma unroll
        for (int j = 0; j < 16; ++j) {
            size_t ci = (size_t)(b * NCH + cb + j) * DI + d;
            hl[j] = h0[ci * NS + n];
            e[j]  = An * sumdt[ci];
        }
#pragma unroll
        for (int j = 0; j < 16; ++j) e[j] = __expf(e[j]);
#pragma unroll
        for (int j = 0; j < 16; ++j) {
            size_t ci = (size_t)(b * NCH + cb + j) * DI + d;
            h0[ci * NS + n] = h;
            h = fmaf(e[j], h, hl[j]);
        }
    }
}

// ---------------- scan pass 3: replay with h_in, fuse y, D-skip, silu(z), bf16 ----------------
__global__ __launch_bounds__(256) void scan_pass3(
    const unsigned short* __restrict__ xch,
    const float* __restrict__ xp, const float* __restrict__ xz,
    const float* __restrict__ dtw, const float* __restrict__ dtb,
    const float* __restrict__ A_log, const float* __restrict__ Dp,
    const float* __restrict__ hin,
    unsigned short* __restrict__ yh)
{
    const int b = blockIdx.z, c = blockIdx.y;
    const int tid = threadIdx.x;
    const int d = blockIdx.x * 256 + tid;
    __shared__ float sxp[CHL * XPW_STRIDE];
    const float* xpsrc = xp + (size_t)(b * L_ + c * CHL) * XPW_STRIDE;
    for (int i = tid; i < CHL * XPW_STRIDE / 4; i += 256)
        ((float4*)sxp)[i] = ((const float4*)xpsrc)[i];
    __syncthreads();

    float Av[NS];
#pragma unroll
    for (int n = 0; n < NS; ++n) Av[n] = -__expf(A_log[(size_t)d * NS + n]);
    const float w = dtw[d], bb = dtb[d], Dv = Dp[d];
    float h[NS];
    const float* hp = hin + ((size_t)(b * NCH + c) * DI + d) * NS;
#pragma unroll
    for (int n = 0; n < NS; n += 4) {
        float4 v = *(const float4*)(hp + n);
        h[n] = v.x; h[n + 1] = v.y; h[n + 2] = v.z; h[n + 3] = v.w;
    }
    size_t off = (size_t)(b * L_ + c * CHL) * DI + d;
    const float* zp  = xz + (size_t)(b * L_ + c * CHL) * (2 * DI) + DI + d;
    unsigned short* yhp = yh + off;

    unsigned short nh = xch[off];
    float nz = zp[0];
    for (int t = 0; t < CHL; ++t) {
        unsigned short ch = nh;
        float zv = nz;
        nh = xch[off + DI];            // prefetch (overrun on last iter, unused)
        nz = zp[(size_t)(t + 1) * (2 * DI)];
        off += DI;
        float xcv = bf2f(ch);
        float dt  = softplusf_(fmaf(sxp[t * XPW_STRIDE], w, bb));
        float u = dt * xcv;
        float y = 0.f;
#pragma unroll
        for (int n = 0; n < NS; ++n) {
            float a = __expf(dt * Av[n]);
            h[n] = fmaf(a, h[n], u * sxp[t * XPW_STRIDE + 1 + n]);
            y = fmaf(h[n], sxp[t * XPW_STRIDE + 17 + n], y);
        }
        float out = fmaf(xcv, Dv, y) * (zv * sigmoidf_(zv));
        yhp[(size_t)t * DI] = f2bf_rn(out);
    }
}

extern "C" void kernel_launch(void* const* d_in, const int* in_sizes, int n_in,
                              void* d_out, int out_size, void* d_ws, size_t ws_size,
                              hipStream_t stream)
{
    (void)in_sizes; (void)n_in; (void)out_size;
    const float* x    = (const float*)d_in[0];
    const float* w1   = (const float*)d_in[1];
    const float* cw   = (const float*)d_in[2];
    const float* cb   = (const float*)d_in[3];
    const float* xpw  = (const float*)d_in[4];
    const float* dtw  = (const float*)d_in[5];
    const float* dtb  = (const float*)d_in[6];
    const float* alog = (const float*)d_in[7];
    const float* Dp   = (const float*)d_in[8];
    const float* w2   = (const float*)d_in[9];
    float* out = (float*)d_out;

    char* ws = (char*)d_ws;
    const size_t MB = 1024 * 1024;
    const size_t KB = 1024;
    if (ws_size < 81 * MB) return;

    // phase-1 overlay [0, 24MB): cast inputs for GEMM1
    unsigned short* x_hi  = (unsigned short*)(ws + 0);        // 4 MB
    unsigned short* w1_hi = (unsigned short*)(ws + 8 * MB);   // 8 MB
    unsigned short* w1_lo = (unsigned short*)(ws + 16 * MB);  // 8 MB
    // xproj-phase overlay (w1 dead after GEMM1):
    float* xp_part = (float*)(ws + 16 * MB);                  // 4 MB (8 x 2048 x 64 f32)
    // scan-phase overlay (x_hi/w1/xp_part dead by then):
    unsigned short* y_hi  = (unsigned short*)(ws + 0);        // 8 MB
    float* h0    = (float*)(ws + 8 * MB);                     // 16 MB (2*64*2048*16 f32)
    float* sumdt = (float*)d_out;                             // 1 MB scratch inside d_out (dead window:
                                                              // written pass1, read pass2, overwritten by reduce4)
    // fixed region:
    float* xz = (float*)(ws + 24 * MB);                       // 32 MB
    float* c_part = (float*)(ws + 24 * MB);                   // 32 MB (GEMM2 split-K partials; xz dead by then)
    unsigned short* xc_hi = (unsigned short*)(ws + 56 * MB);  // 8 MB
    float* xp = (float*)(ws + 72 * MB);                       // 512 KB (2048 x 64)
    unsigned short* wp_hi = (unsigned short*)(ws + 72 * MB + 512 * KB);  // 256 KB
    unsigned short* wp_lo = (unsigned short*)(ws + 72 * MB + 768 * KB);  // 256 KB
    unsigned short* w2_hi = (unsigned short*)(ws + 73 * MB);  // 4 MB

    // fused casts (x hi-only, w1 pair, w2 hi-only, padded x_proj_w pair)
    {
        int total = XN4 + W1N4 + W2N4 + WPN4;
        cast_all_kernel<<<(total + 255) / 256, 256, 0, stream>>>(
            x, w1, w2, xpw, x_hi, w1_hi, w1_lo, w2_hi, wp_hi, wp_lo);
    }

    // GEMM1 (folded 1-term, K=2048 over W1h++W1l): xz[2048][4096]
    {
        dim3 g(4096 / 128, 2048 / 128, 1);
        gemm_fold<128, 128><<<g, 256, 0, stream>>>(x_hi, w1_hi, w1_lo, xz, 2048, 4096, 1024);
    }

    conv_silu_kernel<<<(2048 * 512) / 256, 256, 0, stream>>>(xz, cw, cb, xc_hi);

    // x_proj via split-K MFMA GEMM (M=2048, N=64 padded, K=2048, SK=8), 2-term
    {
        dim3 g(1, 2048 / 64, 8);
        gemm2_xproj<<<g, 256, 0, stream>>>(xc_hi, wp_hi, wp_lo, xp_part);
        xproj_reduce<<<128, 256, 0, stream>>>(xp_part, xp);
    }

    {
        dim3 gs(DI / 256, NCH, B_);
        scan_pass1<<<gs, 256, 0, stream>>>(xc_hi, xp, dtw, dtb, alog, h0, sumdt);
        scan_pass2<<<(B_ * DI * NS) / 256, 256, 0, stream>>>(alog, sumdt, h0);
        scan_pass3<<<gs, 256, 0, stream>>>(xc_hi, xp, xz, dtw, dtb, alog, Dp, h0, y_hi);
    }

    // GEMM2 (1-term: y_hi . W2h): out[2048][1024]
    // split-K=4 (KC=512) -> 512 blocks (2/CU), fp32 partials in c_part, then reduce.
    {
        dim3 g(1024 / 128, 2048 / 128, 4);
        gemm_bt1<128, 128><<<g, 256, 0, stream>>>(y_hi, w2_hi, c_part, 2048, 1024, 2048, 512);
        reduce4_kernel<<<(2048 * 1024 / 4 + 255) / 256, 256, 0, stream>>>(c_part, out, 2048 * 1024 / 4, 2048 * 1024 / 4);
    }
}